// Round 1
// baseline (839.581 us; speedup 1.0000x reference)
//
#include <hip/hip_runtime.h>

#define DTF   0.001f
#define FD_PADC 2
#define PML_WC  20
#define PADC  22
#define NZV   250
#define NYV   350
#define NX    294          // 250 + 44
#define NYW   394          // 350 + 44
#define NSHOT 4
#define NTS   48
#define NRECV 100
#define NCELL (NX*NYW)     // 115836
#define NTOT  (NSHOT*NCELL)

__device__ __forceinline__ float ldz(const float* __restrict__ w, int i, int j) {
    return ((unsigned)i < (unsigned)NX && (unsigned)j < (unsigned)NYW) ? w[i*NYW + j] : 0.f;
}
__device__ __forceinline__ float d1x(const float* __restrict__ w, int i, int j) {
    return (8.f*(ldz(w,i+1,j) - ldz(w,i-1,j)) - (ldz(w,i+2,j) - ldz(w,i-2,j))) * (1.f/60.f);
}
__device__ __forceinline__ float d1y(const float* __restrict__ w, int i, int j) {
    return (8.f*(ldz(w,i,j+1) - ldz(w,i,j-1)) - (ldz(w,i,j+2) - ldz(w,i,j-2))) * (1.f/60.f);
}
__device__ __forceinline__ float d2x(const float* __restrict__ w, int i, int j, float cc) {
    return (-(ldz(w,i+2,j)+ldz(w,i-2,j)) + 16.f*(ldz(w,i+1,j)+ldz(w,i-1,j)) - 30.f*cc) * (1.f/300.f);
}
__device__ __forceinline__ float d2y(const float* __restrict__ w, int i, int j, float cc) {
    return (-(ldz(w,i,j+2)+ldz(w,i,j-2)) + 16.f*(ldz(w,i,j+1)+ldz(w,i,j-1)) - 30.f*cc) * (1.f/300.f);
}

// ---------------- prep ----------------
__global__ void k_vmax(const float* __restrict__ v, float* __restrict__ vmx) {
    __shared__ float sm[256];
    float m = 0.f;
    for (int idx = threadIdx.x; idx < NZV*NYV; idx += 256) m = fmaxf(m, fabsf(v[idx]));
    sm[threadIdx.x] = m; __syncthreads();
    for (int o = 128; o > 0; o >>= 1) {
        if (threadIdx.x < o) sm[threadIdx.x] = fmaxf(sm[threadIdx.x], sm[threadIdx.x+o]);
        __syncthreads();
    }
    if (threadIdx.x == 0) vmx[0] = sm[0];
}

__global__ void k_prep(const float* __restrict__ v, const float* __restrict__ sc,
                       float* __restrict__ v2dt2, float* __restrict__ sterm) {
    int c = blockIdx.x*blockDim.x + threadIdx.x;
    if (c >= NCELL) return;
    int i = c / NYW, j = c - (c / NYW)*NYW;
    int iz = min(max(i - PADC, 0), NZV-1);
    int iy = min(max(j - PADC, 0), NYV-1);
    float vv = v[iz*NYV + iy];
    v2dt2[c] = vv*vv*(DTF*DTF);
    float sp = 0.f;
    if (i >= PADC && i < PADC+NZV && j >= PADC && j < PADC+NYV)
        sp = sc[(i-PADC)*NYV + (j-PADC)];
    sterm[c] = 2.f*vv*sp*(DTF*DTF);
}

__device__ __forceinline__ void prof1(int x, int n, float d, float vmax, float* a, float* b) {
    float fl = fminf(fmaxf((float)(FD_PADC + PML_WC - x)/(float)PML_WC, 0.f), 1.f);
    float fh = fminf(fmaxf((float)(x - (n - 1 - FD_PADC - PML_WC))/(float)PML_WC, 0.f), 1.f);
    float fr = fmaxf(fl, fh);
    float sigma = 3.f*vmax*logf(1000.f)/(2.f*(float)PML_WC*d)*fr*fr;
    float alpha = 3.14159265358979f*25.f*(1.f - fr);
    float bb = expf(-(sigma+alpha)*DTF);
    *a = sigma/(sigma+alpha+1e-9f)*(bb-1.f);
    *b = bb;
}

__global__ void k_prof(const float* __restrict__ vmx,
                       float* __restrict__ axv, float* __restrict__ bxv,
                       float* __restrict__ ayv, float* __restrict__ byv) {
    int x = threadIdx.x;
    float vmax = vmx[0];
    if (x < NX)  prof1(x, NX,  5.0f, vmax, &axv[x], &bxv[x]);
    if (x < NYW) prof1(x, NYW, 5.0f, vmax, &ayv[x], &byv[x]);
}

// ---------------- per-step: phase 1 (PML p-fields) ----------------
__global__ void k_pupd(const float* __restrict__ wf, const float* __restrict__ wsf,
                       float* __restrict__ px, float* __restrict__ py,
                       float* __restrict__ pxs, float* __restrict__ pys,
                       const float* __restrict__ axv, const float* __restrict__ bxv,
                       const float* __restrict__ ayv, const float* __restrict__ byv) {
    int c = blockIdx.x*blockDim.x + threadIdx.x;
    if (c >= NTOT) return;
    int s = c / NCELL; int r = c - s*NCELL;
    int i = r / NYW;   int j = r - i*NYW;
    float ax = axv[i], ay = ayv[j];
    if (ax == 0.f && ay == 0.f) return;   // interior: p stays exactly 0
    const float* w  = wf  + s*NCELL;
    const float* ww = wsf + s*NCELL;
    if (ax != 0.f) {
        float bx = bxv[i];
        px[c]  = bx*px[c]  + ax*d1x(w,  i, j);
        pxs[c] = bx*pxs[c] + ax*d1x(ww, i, j);
    }
    if (ay != 0.f) {
        float by = byv[j];
        py[c]  = by*py[c]  + ay*d1y(w,  i, j);
        pys[c] = by*pys[c] + ay*d1y(ww, i, j);
    }
}

// ---------------- per-step: phase 2 (laplacian + update) ----------------
__global__ void k_step(const float* __restrict__ wf, float* __restrict__ wold,
                       const float* __restrict__ wsf, float* __restrict__ wsold,
                       const float* __restrict__ px, const float* __restrict__ py,
                       float* __restrict__ zx, float* __restrict__ zy,
                       const float* __restrict__ pxs, const float* __restrict__ pys,
                       float* __restrict__ zxs, float* __restrict__ zys,
                       const float* __restrict__ v2dt2, const float* __restrict__ sterm,
                       const float* __restrict__ axv, const float* __restrict__ bxv,
                       const float* __restrict__ ayv, const float* __restrict__ byv,
                       const float* __restrict__ amp, const int* __restrict__ sloc,
                       int t) {
    int c = blockIdx.x*blockDim.x + threadIdx.x;
    if (c >= NTOT) return;
    int s = c / NCELL; int r = c - s*NCELL;
    int i = r / NYW;   int j = r - i*NYW;
    float ax = axv[i], bx = bxv[i], ay = ayv[j], by = byv[j];
    const float* w  = wf  + s*NCELL;
    const float* ww = wsf + s*NCELL;

    // background field
    float wc = w[r];
    float tx = d2x(w, i, j, wc) + d1x(px + s*NCELL, i, j);
    float ty = d2y(w, i, j, wc) + d1y(py + s*NCELL, i, j);
    float zxv = 0.f, zyv = 0.f;
    if (ax != 0.f) { zxv = bx*zx[c] + ax*tx; zx[c] = zxv; }
    if (ay != 0.f) { zyv = by*zy[c] + ay*ty; zy[c] = zyv; }
    float lap = tx + zxv + ty + zyv;
    float vd  = v2dt2[r];
    float wn  = vd*lap + 2.f*wc - wold[c];
    if (i == sloc[s*2] + PADC && j == sloc[s*2+1] + PADC)
        wn += vd * amp[s*NTS + t];
    wold[c] = wn;

    // scattered field
    float wsc = ww[r];
    float txs = d2x(ww, i, j, wsc) + d1x(pxs + s*NCELL, i, j);
    float tys = d2y(ww, i, j, wsc) + d1y(pys + s*NCELL, i, j);
    float zxsv = 0.f, zysv = 0.f;
    if (ax != 0.f) { zxsv = bx*zxs[c] + ax*txs; zxs[c] = zxsv; }
    if (ay != 0.f) { zysv = by*zys[c] + ay*tys; zys[c] = zysv; }
    float lapsc = txs + zxsv + tys + zysv;
    float wsn = vd*lapsc + 2.f*wsc - wsold[c] + sterm[r]*lap;
    wsold[c] = wsn;
}

// ---------------- receiver gather ----------------
__global__ void k_gather(const float* __restrict__ wsn, const int* __restrict__ rloc,
                         float* __restrict__ out, int t) {
    int g = blockIdx.x*blockDim.x + threadIdx.x;
    if (g >= NSHOT*NRECV) return;
    int s = g / NRECV, rr = g - (g / NRECV)*NRECV;
    int ri = rloc[(s*NRECV + rr)*2 + 0] + PADC;
    int rj = rloc[(s*NRECV + rr)*2 + 1] + PADC;
    out[(s*NRECV + rr)*NTS + t] = wsn[s*NCELL + ri*NYW + rj];
}

extern "C" void kernel_launch(void* const* d_in, const int* in_sizes, int n_in,
                              void* d_out, int out_size, void* d_ws, size_t ws_size,
                              hipStream_t stream) {
    const float* v    = (const float*)d_in[0];
    const float* scat = (const float*)d_in[1];
    const float* amp  = (const float*)d_in[2];
    const int*   sloc = (const int*)d_in[3];
    const int*   rloc = (const int*)d_in[4];
    float* out = (float*)d_out;
    float* ws  = (float*)d_ws;

    const size_t F = (size_t)NTOT;
    float* wA  = ws +  0*F;
    float* wB  = ws +  1*F;
    float* px  = ws +  2*F;
    float* py  = ws +  3*F;
    float* zx  = ws +  4*F;
    float* zy  = ws +  5*F;
    float* sA  = ws +  6*F;
    float* sB  = ws +  7*F;
    float* pxs = ws +  8*F;
    float* pys = ws +  9*F;
    float* zxs = ws + 10*F;
    float* zys = ws + 11*F;
    float* v2  = ws + 12*F;
    float* st  = v2 + NCELL;
    float* axv = st + NCELL;
    float* bxv = axv + NX;
    float* ayv = bxv + NX;
    float* byv = ayv + NYW;
    float* vmx = byv + NYW;

    // zero all state fields (harness poisons ws; launch must be deterministic)
    hipMemsetAsync(ws, 0, 12*F*sizeof(float), stream);

    hipLaunchKernelGGL(k_vmax, dim3(1), dim3(256), 0, stream, v, vmx);
    hipLaunchKernelGGL(k_prep, dim3((NCELL+255)/256), dim3(256), 0, stream, v, scat, v2, st);
    hipLaunchKernelGGL(k_prof, dim3(1), dim3(512), 0, stream, vmx, axv, bxv, ayv, byv);

    const int grid = (NTOT + 255)/256;
    float* wc  = wA; float* wp  = wB;
    float* scc = sA; float* scp = sB;
    for (int t = 0; t < NTS; ++t) {
        hipLaunchKernelGGL(k_pupd, dim3(grid), dim3(256), 0, stream,
                           wc, scc, px, py, pxs, pys, axv, bxv, ayv, byv);
        hipLaunchKernelGGL(k_step, dim3(grid), dim3(256), 0, stream,
                           wc, wp, scc, scp, px, py, zx, zy, pxs, pys, zxs, zys,
                           v2, st, axv, bxv, ayv, byv, amp, sloc, t);
        // new fields were written into the "old" buffers -> swap
        float* tmp = wc;  wc  = wp;  wp  = tmp;
        tmp        = scc; scc = scp; scp = tmp;
        hipLaunchKernelGGL(k_gather, dim3(2), dim3(256), 0, stream, scc, rloc, out, t);
    }
}

// Round 2
// 602.808 us; speedup vs baseline: 1.3928x; 1.3928x over previous
//
#include <hip/hip_runtime.h>

#define DTF   0.001f
#define NZV   250
#define NYV   350
#define NX    294          // 250 + 44
#define NYW   394          // 350 + 44
#define PADC  22
#define NSHOT 4
#define NTS   48
#define NRECV 100
#define NCELL (NX*NYW)     // 115836
#define NTOT  (NSHOT*NCELL)
#define XBL   22           // x in [0,21] is low band
#define XBH   (NX-22)      // 272: x >= 272 is high band
#define YBH   (NYW-22)     // 372
#define NB    44
#define PXSZ  (NSHOT*NB*NYW)   // x-band state: [shot][44][NYW]
#define PYSZ  (NSHOT*NX*NB)    // y-band state: [shot][NX][44]
#define NSB   ((NTOT+255)/256) // 1810 stencil blocks
#define GB    2                // gather blocks (400 items)

__device__ __forceinline__ int xbi(int i) {
    return ((unsigned)i < XBL) ? i : ((i >= XBH && i < NX) ? i-(NX-NB) : -1);
}
__device__ __forceinline__ int ybi(int j) {
    return ((unsigned)j < XBL) ? j : ((j >= YBH && j < NYW) ? j-(NYW-NB) : -1);
}

__device__ __forceinline__ float ldz(const float* __restrict__ w, int i, int j) {
    return ((unsigned)i < (unsigned)NX && (unsigned)j < (unsigned)NYW) ? w[i*NYW + j] : 0.f;
}
__device__ __forceinline__ float d1x(const float* __restrict__ w, int i, int j) {
    return (8.f*(ldz(w,i+1,j) - ldz(w,i-1,j)) - (ldz(w,i+2,j) - ldz(w,i-2,j))) * (1.f/60.f);
}
__device__ __forceinline__ float d1y(const float* __restrict__ w, int i, int j) {
    return (8.f*(ldz(w,i,j+1) - ldz(w,i,j-1)) - (ldz(w,i,j+2) - ldz(w,i,j-2))) * (1.f/60.f);
}
__device__ __forceinline__ float d2x(const float* __restrict__ w, int i, int j, float cc) {
    return (-(ldz(w,i+2,j)+ldz(w,i-2,j)) + 16.f*(ldz(w,i+1,j)+ldz(w,i-1,j)) - 30.f*cc) * (1.f/300.f);
}
__device__ __forceinline__ float d2y(const float* __restrict__ w, int i, int j, float cc) {
    return (-(ldz(w,i,j+2)+ldz(w,i,j-2)) + 16.f*(ldz(w,i,j+1)+ldz(w,i,j-1)) - 30.f*cc) * (1.f/300.f);
}

// ---------------- prep ----------------
__global__ void k_vmax(const float* __restrict__ v, unsigned* __restrict__ vmx) {
    __shared__ float sm[256];
    float m = 0.f;
    for (int idx = blockIdx.x*256 + threadIdx.x; idx < NZV*NYV; idx += gridDim.x*256)
        m = fmaxf(m, fabsf(v[idx]));
    sm[threadIdx.x] = m; __syncthreads();
    for (int o = 128; o > 0; o >>= 1) {
        if (threadIdx.x < o) sm[threadIdx.x] = fmaxf(sm[threadIdx.x], sm[threadIdx.x+o]);
        __syncthreads();
    }
    if (threadIdx.x == 0) atomicMax(vmx, __float_as_uint(sm[0]));
}

__global__ void k_prep(const float* __restrict__ v, const float* __restrict__ sc,
                       float* __restrict__ v2dt2, float* __restrict__ sterm) {
    int c = blockIdx.x*blockDim.x + threadIdx.x;
    if (c >= NCELL) return;
    int i = c / NYW, j = c - (c / NYW)*NYW;
    int iz = min(max(i - PADC, 0), NZV-1);
    int iy = min(max(j - PADC, 0), NYV-1);
    float vv = v[iz*NYV + iy];
    v2dt2[c] = vv*vv*(DTF*DTF);
    float sp = 0.f;
    if (i >= PADC && i < PADC+NZV && j >= PADC && j < PADC+NYV)
        sp = sc[(i-PADC)*NYV + (j-PADC)];
    sterm[c] = 2.f*vv*sp*(DTF*DTF);
}

__device__ __forceinline__ void prof1(int x, int n, float d, float vmax, float* a, float* b) {
    float fl = fminf(fmaxf((float)(2 + 20 - x)/20.f, 0.f), 1.f);
    float fh = fminf(fmaxf((float)(x - (n - 23))/20.f, 0.f), 1.f);
    float fr = fmaxf(fl, fh);
    float sigma = 3.f*vmax*logf(1000.f)/(2.f*20.f*d)*fr*fr;
    float alpha = 3.14159265358979f*25.f*(1.f - fr);
    float bb = expf(-(sigma+alpha)*DTF);
    *a = sigma/(sigma+alpha+1e-9f)*(bb-1.f);
    *b = bb;
}

__global__ void k_prof(const unsigned* __restrict__ vmx,
                       float* __restrict__ axv, float* __restrict__ bxv,
                       float* __restrict__ ayv, float* __restrict__ byv) {
    int x = threadIdx.x;
    float vmax = __uint_as_float(vmx[0]);
    if (x < NX)  prof1(x, NX,  5.0f, vmax, &axv[x], &bxv[x]);
    if (x < NYW) prof1(x, NYW, 5.0f, vmax, &ayv[x], &byv[x]);
}

// ---------------- fused step (p-expansion + z + field update + prev gather) ----------------
__global__ __launch_bounds__(256) void k_fstep(
    const float* __restrict__ wf,   float* __restrict__ wold,
    const float* __restrict__ wsf,  float* __restrict__ wsold,
    const float* __restrict__ pxo,  float* __restrict__ pxn,
    const float* __restrict__ pyo,  float* __restrict__ pyn,
    const float* __restrict__ pxso, float* __restrict__ pxsn,
    const float* __restrict__ pyso, float* __restrict__ pysn,
    float* __restrict__ zx,  float* __restrict__ zy,
    float* __restrict__ zxs, float* __restrict__ zys,
    const float* __restrict__ v2, const float* __restrict__ st,
    const float* __restrict__ axv, const float* __restrict__ bxv,
    const float* __restrict__ ayv, const float* __restrict__ byv,
    const float* __restrict__ amp, const int* __restrict__ sloc,
    const int* __restrict__ rloc, float* __restrict__ out, int t)
{
    int bid = blockIdx.x;
    if (bid >= NSB) {
        // gather previous step's scattered output (it is an INPUT buffer here)
        if (t == 0) return;
        int g = (bid - NSB)*256 + threadIdx.x;
        if (g >= NSHOT*NRECV) return;
        int s = g / NRECV, rr = g - s*NRECV;
        int ri = rloc[(s*NRECV+rr)*2+0] + PADC;
        int rj = rloc[(s*NRECV+rr)*2+1] + PADC;
        out[(s*NRECV+rr)*NTS + (t-1)] = wsf[s*NCELL + ri*NYW + rj];
        return;
    }
    int c = bid*256 + threadIdx.x;
    if (c >= NTOT) return;
    int s = c / NCELL; int r = c - s*NCELL;
    int i = r / NYW;   int j = r - i*NYW;

    const float* w  = wf  + s*NCELL;
    const float* ww = wsf + s*NCELL;

    float wc  = w[r];
    float wsc = ww[r];

    float tx  = d2x(w,  i, j, wc);
    float txs = d2x(ww, i, j, wsc);
    float ty  = d2y(w,  i, j, wc);
    float tys = d2y(ww, i, j, wsc);

    int ib = xbi(i);
    int jb = ybi(j);

    // ---- x-direction PML p contribution (recompute p_new at i-2..i+2 on the fly)
    if (i <= XBL+1 || i >= XBH-2) {
        float pv[5], pvs[5];
        #pragma unroll
        for (int k = 0; k < 5; ++k) {
            int ik = i + k - 2; int b = xbi(ik);
            float p = 0.f, ps = 0.f;
            if (b >= 0) {
                float bxk = bxv[ik], axk = axv[ik];
                int o = (s*NB + b)*NYW + j;
                p  = bxk*pxo[o]  + axk*d1x(w,  ik, j);
                ps = bxk*pxso[o] + axk*d1x(ww, ik, j);
            }
            pv[k] = p; pvs[k] = ps;
        }
        tx  += (8.f*(pv[3]-pv[1])  - (pv[4]-pv[0]))  * (1.f/60.f);
        txs += (8.f*(pvs[3]-pvs[1]) - (pvs[4]-pvs[0])) * (1.f/60.f);
        if (ib >= 0) {
            int o = (s*NB + ib)*NYW + j;
            pxn[o] = pv[2]; pxsn[o] = pvs[2];
        }
    }

    // ---- y-direction PML p contribution
    if (j <= XBL+1 || j >= YBH-2) {
        float pv[5], pvs[5];
        #pragma unroll
        for (int k = 0; k < 5; ++k) {
            int jk = j + k - 2; int b = ybi(jk);
            float p = 0.f, ps = 0.f;
            if (b >= 0) {
                float byk = byv[jk], ayk = ayv[jk];
                int o = (s*NX + i)*NB + b;
                p  = byk*pyo[o]  + ayk*d1y(w,  i, jk);
                ps = byk*pyso[o] + ayk*d1y(ww, i, jk);
            }
            pv[k] = p; pvs[k] = ps;
        }
        ty  += (8.f*(pv[3]-pv[1])  - (pv[4]-pv[0]))  * (1.f/60.f);
        tys += (8.f*(pvs[3]-pvs[1]) - (pvs[4]-pvs[0])) * (1.f/60.f);
        if (jb >= 0) {
            int o = (s*NX + i)*NB + jb;
            pyn[o] = pv[2]; pysn[o] = pvs[2];
        }
    }

    // ---- z updates (band-only state, own-cell only: no race)
    float zxv = 0.f, zyv = 0.f, zxsv = 0.f, zysv = 0.f;
    if (ib >= 0) {
        int o = (s*NB + ib)*NYW + j;
        float bx = bxv[i], ax = axv[i];
        zxv  = bx*zx[o]  + ax*tx;  zx[o]  = zxv;
        zxsv = bx*zxs[o] + ax*txs; zxs[o] = zxsv;
    }
    if (jb >= 0) {
        int o = (s*NX + i)*NB + jb;
        float by = byv[j], ay = ayv[j];
        zyv  = by*zy[o]  + ay*ty;  zy[o]  = zyv;
        zysv = by*zys[o] + ay*tys; zys[o] = zysv;
    }

    float lap  = tx + zxv + ty + zyv;
    float laps = txs + zxsv + tys + zysv;
    float vd   = v2[r];
    float wn   = vd*lap + 2.f*wc - wold[c];
    if (i == sloc[s*2] + PADC && j == sloc[s*2+1] + PADC)
        wn += vd * amp[s*NTS + t];
    float wsn = vd*laps + 2.f*wsc - wsold[c] + st[r]*lap;
    wold[c]  = wn;
    wsold[c] = wsn;
}

// ---------------- tail gather (t = NTS-1) ----------------
__global__ void k_gtail(const float* __restrict__ wsn, const int* __restrict__ rloc,
                        float* __restrict__ out) {
    int g = blockIdx.x*blockDim.x + threadIdx.x;
    if (g >= NSHOT*NRECV) return;
    int s = g / NRECV, rr = g - s*NRECV;
    int ri = rloc[(s*NRECV+rr)*2+0] + PADC;
    int rj = rloc[(s*NRECV+rr)*2+1] + PADC;
    out[(s*NRECV+rr)*NTS + (NTS-1)] = wsn[s*NCELL + ri*NYW + rj];
}

extern "C" void kernel_launch(void* const* d_in, const int* in_sizes, int n_in,
                              void* d_out, int out_size, void* d_ws, size_t ws_size,
                              hipStream_t stream) {
    const float* v    = (const float*)d_in[0];
    const float* scat = (const float*)d_in[1];
    const float* amp  = (const float*)d_in[2];
    const int*   sloc = (const int*)d_in[3];
    const int*   rloc = (const int*)d_in[4];
    float* out = (float*)d_out;
    float* ws  = (float*)d_ws;

    const size_t F = (size_t)NTOT;
    float* wA   = ws;
    float* wB   = wA + F;
    float* sA   = wB + F;
    float* sB   = sA + F;
    float* pxA  = sB + F;
    float* pxB  = pxA + PXSZ;
    float* pxsA = pxB + PXSZ;
    float* pxsB = pxsA + PXSZ;
    float* zx   = pxsB + PXSZ;
    float* zxs  = zx + PXSZ;
    float* pyA  = zxs + PXSZ;
    float* pyB  = pyA + PYSZ;
    float* pysA = pyB + PYSZ;
    float* pysB = pysA + PYSZ;
    float* zy   = pysB + PYSZ;
    float* zys  = zy + PYSZ;
    float* vmxf = zys + PYSZ;          // 1 float (as unsigned)
    float* v2   = vmxf + 1;
    float* st   = v2 + NCELL;
    float* axv  = st + NCELL;
    float* bxv  = axv + NX;
    float* ayv  = bxv + NX;
    float* byv  = ayv + NYW;
    unsigned* vmx = (unsigned*)vmxf;

    // zero all recurrence state + vmax accumulator (one memset)
    size_t zero_floats = 4*F + 6*(size_t)PXSZ + 6*(size_t)PYSZ + 1;
    hipMemsetAsync(ws, 0, zero_floats*sizeof(float), stream);

    hipLaunchKernelGGL(k_vmax, dim3(64), dim3(256), 0, stream, v, vmx);
    hipLaunchKernelGGL(k_prep, dim3((NCELL+255)/256), dim3(256), 0, stream, v, scat, v2, st);
    hipLaunchKernelGGL(k_prof, dim3(1), dim3(512), 0, stream, vmx, axv, bxv, ayv, byv);

    float* wc  = wA;  float* wp  = wB;
    float* scc = sA;  float* scp = sB;
    float* pxc = pxA; float* pxn = pxB;
    float* pyc = pyA; float* pyn = pyB;
    float* pxsc = pxsA; float* pxsn = pxsB;
    float* pysc = pysA; float* pysn = pysB;

    for (int t = 0; t < NTS; ++t) {
        hipLaunchKernelGGL(k_fstep, dim3(NSB + GB), dim3(256), 0, stream,
                           wc, wp, scc, scp,
                           pxc, pxn, pyc, pyn, pxsc, pxsn, pysc, pysn,
                           zx, zy, zxs, zys,
                           v2, st, axv, bxv, ayv, byv,
                           amp, sloc, rloc, out, t);
        float* tmp;
        tmp = wc;  wc  = wp;  wp  = tmp;
        tmp = scc; scc = scp; scp = tmp;
        tmp = pxc; pxc = pxn; pxn = tmp;
        tmp = pyc; pyc = pyn; pyn = tmp;
        tmp = pxsc; pxsc = pxsn; pxsn = tmp;
        tmp = pysc; pysc = pysn; pysn = tmp;
    }
    hipLaunchKernelGGL(k_gtail, dim3(2), dim3(256), 0, stream, scc, rloc, out);
}